// Round 1
// baseline (82.120 us; speedup 1.0000x reference)
//
#include <hip/hip_runtime.h>

// conv_capsules: extract overlapping 3x3 capsule patches.
// x: [B=8, H=64, W=64, C=16, D=16] f32 -> out: [B, OH=62, OW=62, KH=3, KW=3, C, D] f32 (flat)
// out[b,oh,ow,kh,kw,c,d] = x[b,oh+kh,ow+kw,c,d]
// Pure data movement; inner C*D = 256 floats contiguous on both sides.

constexpr int B  = 8;
constexpr int H  = 64;
constexpr int W  = 64;
constexpr int KH = 3;
constexpr int KW = 3;
constexpr int OH = H - KH + 1;  // 62
constexpr int OW = W - KW + 1;  // 62
constexpr int CD  = 16 * 16;    // 256 floats per (b,h,w) "pixel"
constexpr int CD4 = CD / 4;     // 64 float4 per pixel

__global__ __launch_bounds__(256) void conv_capsules_patch_kernel(
    const float4* __restrict__ in, float4* __restrict__ out, int total4)
{
    const int stride = gridDim.x * blockDim.x;
    for (int i = blockIdx.x * blockDim.x + threadIdx.x; i < total4; i += stride) {
        const int lane = i & (CD4 - 1);   // float4 index within the 1KB pixel
        int t = i >> 6;                   // tile = (b,oh,ow,kh,kw)
        const int kw = t % KW; t /= KW;
        const int kh = t % KH; t /= KH;
        const int ow = t % OW; t /= OW;
        const int oh = t % OH; t /= OH;
        const int b  = t;
        const int h = oh + kh;
        const int w = ow + kw;
        const int in_idx = ((b * H + h) * W + w) * CD4 + lane;
        out[i] = in[in_idx];
    }
}

extern "C" void kernel_launch(void* const* d_in, const int* in_sizes, int n_in,
                              void* d_out, int out_size, void* d_ws, size_t ws_size,
                              hipStream_t stream)
{
    const float4* in  = (const float4*)d_in[0];
    float4*       out = (float4*)d_out;
    const int total4 = out_size / 4;  // 17,713,152

    const int block = 256;
    const int grid  = 4096;           // grid-stride; ~34 float4 per thread
    conv_capsules_patch_kernel<<<grid, block, 0, stream>>>(in, out, total4);
}